// Round 10
// baseline (46.833 us; speedup 1.0000x reference)
//
#include <hip/hip_runtime.h>

#define HH 80
#define WW 80
#define IMG (HH * WW)             // 6400
#define NV ((HH - 1) * WW)        // 6320 vertical edge slots
#define NPTS (NV + HH * (WW - 1)) // 12640 edge slots per image
#define NPIX (2 * IMG)            // 12800
#define BIGF 1.0e10f
#define INVC 1.0e7f
#define EPSF 1e-8f
#define QSCALE 131072.0f          // 2^17 fixed point (exact-commutative sums)

// k_prep geometry
#define SETPAD 12800
#define SBLOCKS (SETPAD / 256)    // 50 blocks per set
#define EXBLOCKS (4 * SBLOCKS)    // 200 extraction blocks
#define PXBLOCKS (NPIX / 256)     // 50 pixel blocks
#define PREPB (EXBLOCKS + PXBLOCKS) // 250

// k_min geometry
#define BLK 256                   // 4 waves
#define APT 8                     // A points per thread
#define ACHUNK (BLK * APT)        // 2048
#define ABLOCKS ((NPTS + ACHUNK - 1) / ACHUNK) // 7 worst case
#define NSLICE 32
#define MAXSLICE ((((NPTS + NSLICE - 1) / NSLICE) + 1) & ~1) // 396
#define AROW 6400                 // padded per-(dir,slice) row stride (floats)

// k_fin geometry
#define FINB 32                   // 8 blocks per set
#define FQ 8

// scalar ws layout (each contended counter on its own 128-B line)
#define CNT_STRIDE 32             // ints; cnt[set] at d_ws + set*128
#define TICKET_OFF 640
#define SUM_OFF 768               // 4 x u64
#define SCALAR_BYTES 1024
#define PIXPART_OFF 1024          // u64[50], plain stores (no zero needed)
#define PTS_OFF 2048

__device__ __forceinline__ long long wave_reduce_ll(long long v) {
#pragma unroll
  for (int o = 32; o > 0; o >>= 1) {
    int2 p = *(int2*)&v;
    p.x = __shfl_down(p.x, o, 64);
    p.y = __shfl_down(p.y, o, 64);
    v += *(long long*)&p;
  }
  return v;
}

// --------------------------------------------------------------- k_zero
__global__ void k_zero(unsigned int* __restrict__ w) {
  w[threadIdx.x] = 0u;   // 256 threads x 4 B = 1024 B (cnt, ticket, sum_i)
}

// --------------------------------------------------------------- k_prep
// 250 blocks. Blocks 0..199: zero-crossing extraction, block-aggregated
// atomic append (1 atomicAdd/block, counters on separate lines). Blocks
// 200..249: pixel loss partials in exact int64, plain per-block stores.
// Append ORDER is non-deterministic but all consumers are order-invariant
// and exact (multiset min; int64 sums) -> output bitwise stable.
__global__ void __launch_bounds__(256) k_prep(
    const float* __restrict__ pred, const float* __restrict__ gt,
    float2* __restrict__ pts, int* __restrict__ cnt,
    unsigned long long* __restrict__ pixpart) {
  __shared__ int wc[4], wo[4];
  __shared__ long long rl[4];
  int tid = threadIdx.x, lane = tid & 63, wid = tid >> 6;

  if (blockIdx.x < EXBLOCKS) {
    int set = blockIdx.x / SBLOCKS;
    int idx = (blockIdx.x % SBLOCKS) * 256 + tid;   // slot in [0, SETPAD)
    const float* s = (set < 2 ? pred : gt) + (set & 1) * IMG;
    float r = 0.f, c = 0.f;
    bool valid = false;
    if (idx < NPTS) {
      if (idx < NV) {
        int i = idx / WW, j = idx - i * WW;
        float v1 = s[i * WW + j], v2 = s[(i + 1) * WW + j];
        c = (float)j;
        if (v1 == 0.f)      { r = (float)i;       valid = true; }
        else if (v2 == 0.f) { r = (float)i + 1.f; valid = true; }
        else {
          r = (float)i + fabsf(v1) / (fabsf(v1) + fabsf(v2) + EPSF);
          valid = (v1 * v2 < 0.f);
        }
      } else {
        int t = idx - NV;
        int i = t / (WW - 1), j = t - i * (WW - 1);
        float h1 = s[i * WW + j], h2 = s[i * WW + j + 1];
        r = (float)i;
        if (h1 == 0.f)      { c = (float)j;       valid = true; }
        else if (h2 == 0.f) { c = (float)j + 1.f; valid = true; }
        else {
          c = (float)j + fabsf(h1) / (fabsf(h1) + fabsf(h2) + EPSF);
          valid = (h1 * h2 < 0.f);
        }
      }
    }
    unsigned long long mask = __ballot(valid);
    int nw = __popcll(mask);
    if (lane == 0) wc[wid] = nw;
    __syncthreads();
    if (tid == 0) {
      int t0 = wc[0], t1 = wc[1], t2 = wc[2], t3 = wc[3];
      int tot = t0 + t1 + t2 + t3;
      int base = tot ? atomicAdd(&cnt[set * CNT_STRIDE], tot) : 0;
      wo[0] = base; wo[1] = base + t0; wo[2] = base + t0 + t1;
      wo[3] = base + t0 + t1 + t2;
    }
    __syncthreads();
    if (valid) {
      int lpos = __popcll(mask & ((1ull << lane) - 1ull));
      pts[set * NPTS + wo[wid] + lpos] = make_float2(r, c);
    }
  } else {
    int b = blockIdx.x - EXBLOCKS;
    int p = b * 256 + tid;
    float d = fabsf(pred[p] - gt[p]);
    long long q = (long long)(d * QSCALE + 0.5f);
    q = wave_reduce_ll(q);
    if (lane == 0) rl[wid] = q;
    __syncthreads();
    if (tid == 0)
      pixpart[b] = (unsigned long long)(rl[0] + rl[1] + rl[2] + rl[3]);
  }
}

// --------------------------------------------------------------- k_min
// dir 0: A=0 B=2 | 1: A=2 B=0 | 2: A=1 B=3 | 3: A=3 B=1
// min over b of (q2 - 2px*qx - 2py*qy); +p2 and sqrt are monotone.
// NO atomics: each block writes its per-slice min row with plain coalesced
// stores; k_fin reduces across slices. (r2..r9 evidence: ~1M device
// atomicMins were the k_min ceiling.)
__global__ void __launch_bounds__(BLK) k_min(
    const float2* __restrict__ pts, float* __restrict__ minarr2,
    const int* __restrict__ cnt) {
  int dir = blockIdx.z;
  int Aset = ((dir & 1) << 1) | (dir >> 1);
  int Bset = Aset ^ 2;
  int cntA = cnt[Aset * CNT_STRIDE], cntB = cnt[Bset * CNT_STRIDE];

  int abase0 = blockIdx.x * ACHUNK;
  if (abase0 >= cntA) return;
  int slicelen = (((cntB + NSLICE - 1) / NSLICE) + 1) & ~1;
  int b0 = blockIdx.y * slicelen;
  if (b0 >= cntB) return;
  int n = min(slicelen, cntB - b0);
  int sn = (n + 1) & ~1;  // pad to even with a dummy far point

  __shared__ float4 tile[MAXSLICE];
  for (int i = threadIdx.x; i < sn; i += BLK) {
    float2 q = (i < n) ? pts[Bset * NPTS + b0 + i] : make_float2(INVC, INVC);
    tile[i] = make_float4(q.x, q.y, fmaf(q.x, q.x, q.y * q.y), 0.f);
  }
  __syncthreads();

  int abase = abase0 + threadIdx.x;
  float nx[APT], ny[APT], p2[APT], m[APT];
#pragma unroll
  for (int i = 0; i < APT; ++i) {
    int a = abase + i * BLK;
    float2 p = (a < cntA) ? pts[Aset * NPTS + a] : make_float2(0.f, 0.f);
    nx[i] = -2.f * p.x;
    ny[i] = -2.f * p.y;
    p2[i] = fmaf(p.x, p.x, p.y * p.y);
    m[i] = 3.0e38f;
  }

#pragma unroll 2
  for (int b = 0; b < sn; b += 2) {
    float4 q0 = tile[b];
    float4 q1 = tile[b + 1];
#pragma unroll
    for (int i = 0; i < APT; ++i) {
      float t0 = fmaf(ny[i], q0.y, fmaf(nx[i], q0.x, q0.z));
      float t1 = fmaf(ny[i], q1.y, fmaf(nx[i], q1.x, q1.z));
      m[i] = fminf(fminf(t0, t1), m[i]);   // -> v_min3_f32
    }
  }

  float* row = minarr2 + (size_t)(dir * NSLICE + blockIdx.y) * AROW;
#pragma unroll
  for (int i = 0; i < APT; ++i) {
    int a = abase + i * BLK;
    if (a < cntA) row[a] = fmaxf(m[i] + p2[i], 0.f);  // plain coalesced store
  }
}

// --------------------------------------------------------------- k_fin
// 32 blocks (8 per set): per A-point min over valid slices (coalesced
// wave-loads at stride AROW), sqrt, exact int64 partial sums, device
// atomicAdd. Ticketed last block combines + writes out. 32 fences = cheap.
__global__ void __launch_bounds__(256) k_fin(
    const float* __restrict__ minarr2, const int* __restrict__ cnt,
    const unsigned long long* __restrict__ pixpart,
    unsigned long long* __restrict__ sum_i,
    unsigned int* __restrict__ ticket, float* __restrict__ out) {
  int set = blockIdx.x >> 3, q = blockIdx.x & 7;
  int tid = threadIdx.x, lane = tid & 63;
  int dir = ((set & 1) << 1) | (set >> 1);   // dir whose A-set == set
  int n = cnt[set * CNT_STRIDE];
  int cntB = cnt[(set ^ 2) * CNT_STRIDE];
  int slicelen = (((cntB + NSLICE - 1) / NSLICE) + 1) & ~1;
  int nsv = (slicelen > 0) ? min(NSLICE, (cntB + slicelen - 1) / slicelen) : 0;
  const float* base = minarr2 + (size_t)dir * NSLICE * AROW;

  long long ls = 0;
  for (int a = q * 256 + tid; a < n; a += FQ * 256) {
    float m0 = BIGF, m1 = BIGF, m2 = BIGF, m3 = BIGF;
    int s = 0;
    for (; s + 4 <= nsv; s += 4) {
      m0 = fminf(m0, base[(size_t)(s + 0) * AROW + a]);
      m1 = fminf(m1, base[(size_t)(s + 1) * AROW + a]);
      m2 = fminf(m2, base[(size_t)(s + 2) * AROW + a]);
      m3 = fminf(m3, base[(size_t)(s + 3) * AROW + a]);
    }
    for (; s < nsv; ++s) m0 = fminf(m0, base[(size_t)s * AROW + a]);
    float m = fminf(fminf(m0, m1), fminf(m2, m3));
    ls += (long long)(sqrtf(m) * QSCALE + 0.5f);
  }
  ls = wave_reduce_ll(ls);
  if (lane == 0) atomicAdd(&sum_i[set], (unsigned long long)ls);
  __syncthreads();

  if (tid < 64) {
    long long pv = (lane < PXBLOCKS) ? (long long)pixpart[lane] : 0ll;
    pv = wave_reduce_ll(pv);
    if (lane == 0) {
      __threadfence();
      unsigned int t = atomicAdd(ticket, 1u);
      if (t == FINB - 1) {  // all blocks' adds complete (device-scope atomics)
        const float iq = 1.0f / QSCALE;
        float ss[4];
        for (int k = 0; k < 4; ++k)
          ss[k] = (float)((long long)atomicAdd(&sum_i[k], 0ull)) * iq;
        float n0 = fmaxf((float)cnt[0 * CNT_STRIDE], 1.f);
        float n1 = fmaxf((float)cnt[1 * CNT_STRIDE], 1.f);
        float n2 = fmaxf((float)cnt[2 * CNT_STRIDE], 1.f);
        float n3 = fmaxf((float)cnt[3 * CNT_STRIDE], 1.f);
        float ch0 = -ss[0] / n0 + ss[2] / n2;
        float ch1 = -ss[1] / n1 + ss[3] / n3;
        out[0] = (float)pv * iq / (float)NPIX;
        out[1] = 0.5f * (ch0 + ch1);
      }
    }
  }
}

extern "C" void kernel_launch(void* const* d_in, const int* in_sizes, int n_in,
                              void* d_out, int out_size, void* d_ws, size_t ws_size,
                              hipStream_t stream) {
  const float* pred = (const float*)d_in[0];
  const float* gt   = (const float*)d_in[1];
  float* out = (float*)d_out;

  // ws: scalars | pixpart u64[50] | 4*NPTS float2 pts | minarr2[4][NSLICE][AROW]
  int* cnt = (int*)d_ws;                                                // lines @0,128,256,384
  unsigned int* ticket = (unsigned int*)((char*)d_ws + TICKET_OFF);
  unsigned long long* sum_i = (unsigned long long*)((char*)d_ws + SUM_OFF);
  unsigned long long* pixpart = (unsigned long long*)((char*)d_ws + PIXPART_OFF);
  float2* pts = (float2*)((char*)d_ws + PTS_OFF);
  float* minarr2 = (float*)((char*)d_ws + PTS_OFF + sizeof(float2) * 4 * NPTS);

  k_zero<<<1, 256, 0, stream>>>((unsigned int*)d_ws);
  k_prep<<<PREPB, 256, 0, stream>>>(pred, gt, pts, cnt, pixpart);
  k_min<<<dim3(ABLOCKS, NSLICE, 4), BLK, 0, stream>>>(pts, minarr2, cnt);
  k_fin<<<FINB, 256, 0, stream>>>(minarr2, cnt, pixpart, sum_i, ticket, out);
}

// Round 11
// 38.475 us; speedup vs baseline: 1.2172x; 1.2172x over previous
//
#include <hip/hip_runtime.h>

#define HH 80
#define WW 80
#define IMG (HH * WW)             // 6400
#define NV ((HH - 1) * WW)        // 6320 vertical edge slots
#define NPTS (NV + HH * (WW - 1)) // 12640 edge slots per image
#define NPIX (2 * IMG)            // 12800
#define BIGF 1.0e10f
#define INVC 1.0e7f
#define EPSF 1e-8f
#define QSCALE 131072.0f          // 2^17 fixed point (exact-commutative sums)

// k_prep geometry: each set padded to 12800 slots = 50 blocks x 256 threads
#define SETPAD 12800
#define SBLOCKS (SETPAD / 256)    // 50 blocks per set
#define EXBLOCKS (4 * SBLOCKS)    // 200 extraction blocks
#define PXBLOCKS (NPIX / 256)     // 50 pixel blocks
#define PREPB (EXBLOCKS + PXBLOCKS) // 250

// k_min geometry
#define BLK 256                   // 4 waves
#define APT 8                     // A points per thread
#define ACHUNK (BLK * APT)        // 2048
#define ABLOCKS ((NPTS + ACHUNK - 1) / ACHUNK) // 7 worst case; ~4 active
#define NSLICE 32
#define MAXSLICE ((((NPTS + NSLICE - 1) / NSLICE) + 1) & ~1) // 396
#define MAXP2 (MAXSLICE / 2)      // 198 f32x2 pairs

// scalar ws layout (each contended counter on its own 128-B line)
#define CNT_STRIDE 32             // ints; cnt[set] at d_ws + set*128
#define PIX_OFF 512
#define TICKET_OFF 640
#define SUM_OFF 768               // 4 x u64
#define SCALAR_BYTES 1024

typedef float f32x2 __attribute__((ext_vector_type(2)));

__device__ __forceinline__ long long wave_reduce_ll(long long v) {
#pragma unroll
  for (int o = 32; o > 0; o >>= 1) {
    int2 p = *(int2*)&v;
    p.x = __shfl_down(p.x, o, 64);
    p.y = __shfl_down(p.y, o, 64);
    v += *(long long*)&p;
  }
  return v;
}

// --------------------------------------------------------------- k_zero
__global__ void k_zero(unsigned int* __restrict__ w) {
  w[threadIdx.x] = 0u;   // 256 threads x 4 B = 1024 B (cnt, pix, ticket, sum_i)
}

// --------------------------------------------------------------- k_prep
// 250 blocks. minarr init + (blocks 0..199) zero-crossing extraction with
// block-aggregated atomic append (one atomicAdd per block, counters on
// separate cache lines) + (blocks 200..249) pixel loss in exact int64.
// Append ORDER is non-deterministic, but all consumers are order-invariant
// and exact (multiset min; int64 sums) -> output bitwise stable.
__global__ void __launch_bounds__(256) k_prep(
    const float* __restrict__ pred, const float* __restrict__ gt,
    float2* __restrict__ pts, float* __restrict__ minarr,
    int* __restrict__ cnt, unsigned long long* __restrict__ pix_i) {
  __shared__ int wc[4], wo[4];
  __shared__ long long rl[4];
  int tid = threadIdx.x, lane = tid & 63, wid = tid >> 6;
  int gtid = blockIdx.x * 256 + tid;

  if (gtid < 4 * NPTS) minarr[gtid] = BIGF;

  if (blockIdx.x < EXBLOCKS) {
    int set = blockIdx.x / SBLOCKS;
    int idx = (blockIdx.x % SBLOCKS) * 256 + tid;   // slot in [0, SETPAD)
    const float* s = (set < 2 ? pred : gt) + (set & 1) * IMG;
    float r = 0.f, c = 0.f;
    bool valid = false;
    if (idx < NPTS) {
      if (idx < NV) {
        int i = idx / WW, j = idx - i * WW;
        float v1 = s[i * WW + j], v2 = s[(i + 1) * WW + j];
        c = (float)j;
        if (v1 == 0.f)      { r = (float)i;       valid = true; }
        else if (v2 == 0.f) { r = (float)i + 1.f; valid = true; }
        else {
          r = (float)i + fabsf(v1) / (fabsf(v1) + fabsf(v2) + EPSF);
          valid = (v1 * v2 < 0.f);
        }
      } else {
        int t = idx - NV;
        int i = t / (WW - 1), j = t - i * (WW - 1);
        float h1 = s[i * WW + j], h2 = s[i * WW + j + 1];
        r = (float)i;
        if (h1 == 0.f)      { c = (float)j;       valid = true; }
        else if (h2 == 0.f) { c = (float)j + 1.f; valid = true; }
        else {
          c = (float)j + fabsf(h1) / (fabsf(h1) + fabsf(h2) + EPSF);
          valid = (h1 * h2 < 0.f);
        }
      }
    }
    unsigned long long mask = __ballot(valid);
    int nw = __popcll(mask);
    if (lane == 0) wc[wid] = nw;
    __syncthreads();
    if (tid == 0) {
      int t0 = wc[0], t1 = wc[1], t2 = wc[2], t3 = wc[3];
      int tot = t0 + t1 + t2 + t3;
      int base = tot ? atomicAdd(&cnt[set * CNT_STRIDE], tot) : 0;
      wo[0] = base; wo[1] = base + t0; wo[2] = base + t0 + t1;
      wo[3] = base + t0 + t1 + t2;
    }
    __syncthreads();
    if (valid) {
      int lpos = __popcll(mask & ((1ull << lane) - 1ull));
      pts[set * NPTS + wo[wid] + lpos] = make_float2(r, c);
    }
  } else {
    int p = (blockIdx.x - EXBLOCKS) * 256 + tid;
    float d = fabsf(pred[p] - gt[p]);
    long long q = (long long)(d * QSCALE + 0.5f);
    q = wave_reduce_ll(q);
    if (lane == 0) rl[wid] = q;
    __syncthreads();
    if (tid == 0)
      atomicAdd(pix_i, (unsigned long long)(rl[0] + rl[1] + rl[2] + rl[3]));
  }
}

// --------------------------------------------------------------- k_min
// dir 0: A=0 B=2 | 1: A=2 B=0 | 2: A=1 B=3 | 3: A=3 B=1
// min over b of (q2 - 2px*qx - 2py*qy); +p2 and sqrt are monotone (sqrt in k_fin).
// Inner loop: v_pk_fma_f32 via __builtin_elementwise_fma on f32x2 (SoA LDS
// tile) -> 2 pk_fma + 1 min3 per A per 2 B-points = 1.5 instr/pair (was 2.5).
// Arithmetic identical to scalar (same fma rounding) -> bitwise-stable result.
__global__ void __launch_bounds__(BLK) k_min(
    const float2* __restrict__ pts, float* __restrict__ minarr,
    const int* __restrict__ cnt) {
  int dir = blockIdx.z;
  int Aset = ((dir & 1) << 1) | (dir >> 1);
  int Bset = Aset ^ 2;
  int cntA = cnt[Aset * CNT_STRIDE], cntB = cnt[Bset * CNT_STRIDE];

  int abase0 = blockIdx.x * ACHUNK;
  if (abase0 >= cntA) return;
  int slicelen = (((cntB + NSLICE - 1) / NSLICE) + 1) & ~1;
  int b0 = blockIdx.y * slicelen;
  if (b0 >= cntB) return;
  int n = min(slicelen, cntB - b0);
  int sn = (n + 1) & ~1;  // pad to even with a dummy far point

  __shared__ f32x2 qx_s[MAXP2], qy_s[MAXP2], q2_s[MAXP2];
  for (int i = threadIdx.x; i < sn; i += BLK) {
    float2 q = (i < n) ? pts[Bset * NPTS + b0 + i] : make_float2(INVC, INVC);
    ((float*)qx_s)[i] = q.x;
    ((float*)qy_s)[i] = q.y;
    ((float*)q2_s)[i] = fmaf(q.x, q.x, q.y * q.y);
  }
  __syncthreads();

  int abase = abase0 + threadIdx.x;
  f32x2 nxv[APT], nyv[APT];
  float p2v[APT], m[APT];
#pragma unroll
  for (int i = 0; i < APT; ++i) {
    int a = abase + i * BLK;
    float2 p = (a < cntA) ? pts[Aset * NPTS + a] : make_float2(0.f, 0.f);
    float nx = -2.f * p.x, ny = -2.f * p.y;
    nxv[i].x = nx; nxv[i].y = nx;
    nyv[i].x = ny; nyv[i].y = ny;
    p2v[i] = fmaf(p.x, p.x, p.y * p.y);
    m[i] = 3.0e38f;
  }

  int np2 = sn >> 1;
#pragma unroll 2
  for (int p = 0; p < np2; ++p) {
    f32x2 qx = qx_s[p], qy = qy_s[p], q2 = q2_s[p];
#pragma unroll
    for (int i = 0; i < APT; ++i) {
      f32x2 u = __builtin_elementwise_fma(
          nyv[i], qy, __builtin_elementwise_fma(nxv[i], qx, q2));
      m[i] = fminf(fminf(u.x, u.y), m[i]);   // -> v_min3_f32
    }
  }

#pragma unroll
  for (int i = 0; i < APT; ++i) {
    int a = abase + i * BLK;
    if (a < cntA) {
      float d2 = fmaxf(m[i] + p2v[i], 0.f);
      // non-negative floats order as uint bit patterns; min is order-exact
      atomicMin((unsigned int*)&minarr[Aset * NPTS + a], __float_as_uint(d2));
    }
  }
}

// --------------------------------------------------------------- k_fin
// 16 blocks (4 per set): exact int64 partial sums of round(sqrt(d2)*2^17),
// device-scope atomicAdd (order-independent, bit-exact). Ticketed last block
// combines and writes the two outputs. 16 device fences total = cheap.
__global__ void __launch_bounds__(256) k_fin(
    const float* __restrict__ minarr, const int* __restrict__ cnt,
    const unsigned long long* __restrict__ pix_i,
    unsigned long long* __restrict__ sum_i,
    unsigned int* __restrict__ ticket, float* __restrict__ out) {
  int set = blockIdx.x >> 2, q = blockIdx.x & 3;
  int tid = threadIdx.x, lane = tid & 63;
  int n = cnt[set * CNT_STRIDE];

  long long ls = 0;
  for (int i = q * 256 + tid; i < n; i += 1024) {
    float d = sqrtf(minarr[set * NPTS + i]);
    ls += (long long)(d * QSCALE + 0.5f);
  }
  ls = wave_reduce_ll(ls);
  if (lane == 0) atomicAdd(&sum_i[set], (unsigned long long)ls);
  __syncthreads();

  if (tid == 0) {
    __threadfence();
    unsigned int t = atomicAdd(ticket, 1u);
    if (t == 15u) {  // all 16 blocks' adds complete (device-scope atomics)
      const float iq = 1.0f / QSCALE;
      float ss[4];
      for (int k = 0; k < 4; ++k)
        ss[k] = (float)((long long)atomicAdd(&sum_i[k], 0ull)) * iq;
      float n0 = fmaxf((float)cnt[0 * CNT_STRIDE], 1.f);
      float n1 = fmaxf((float)cnt[1 * CNT_STRIDE], 1.f);
      float n2 = fmaxf((float)cnt[2 * CNT_STRIDE], 1.f);
      float n3 = fmaxf((float)cnt[3 * CNT_STRIDE], 1.f);
      float ch0 = -ss[0] / n0 + ss[2] / n2;
      float ch1 = -ss[1] / n1 + ss[3] / n3;
      out[0] = (float)(long long)(*pix_i) * iq / (float)NPIX;
      out[1] = 0.5f * (ch0 + ch1);
    }
  }
}

extern "C" void kernel_launch(void* const* d_in, const int* in_sizes, int n_in,
                              void* d_out, int out_size, void* d_ws, size_t ws_size,
                              hipStream_t stream) {
  const float* pred = (const float*)d_in[0];
  const float* gt   = (const float*)d_in[1];
  float* out = (float*)d_out;

  // ws: [0..1023] scalars (zeroed by k_zero) | 4*NPTS float2 pts | 4*NPTS float mins
  int* cnt = (int*)d_ws;                                                // lines @0,128,256,384
  unsigned long long* pix_i = (unsigned long long*)((char*)d_ws + PIX_OFF);
  unsigned int* ticket = (unsigned int*)((char*)d_ws + TICKET_OFF);
  unsigned long long* sum_i = (unsigned long long*)((char*)d_ws + SUM_OFF);
  float2* pts   = (float2*)((char*)d_ws + SCALAR_BYTES);
  float* minarr = (float*)((char*)d_ws + SCALAR_BYTES + sizeof(float2) * 4 * NPTS);

  k_zero<<<1, 256, 0, stream>>>((unsigned int*)d_ws);
  k_prep<<<PREPB, 256, 0, stream>>>(pred, gt, pts, minarr, cnt, pix_i);
  k_min<<<dim3(ABLOCKS, NSLICE, 4), BLK, 0, stream>>>(pts, minarr, cnt);
  k_fin<<<16, 256, 0, stream>>>(minarr, cnt, pix_i, sum_i, ticket, out);
}